// Round 1
// baseline (1708.967 us; speedup 1.0000x reference)
//
#include <hip/hip_runtime.h>
#include <stdint.h>

// Fused attention: out = dropout(softmax(Q K^T * scale + mask)) @ V
// B=1, H=128, S=256, D=2048, fp32 in/out.
// Round 1: correctness-first fp32 vector kernel. bf16 MFMA comes later.

#define NH   128
#define SEQ  256
#define DIM  2048
#define TQ   32        // query rows per block
#define DC1  16        // d-chunk (phase 1)
#define WTP  36        // padded row stride of Wt in floats (144 B, 16B-aligned)
#define NTHR 256

// ---------- threefry2x32, JAX key = random.key(42) -> (k0,k1)=(0,42) --------
// JAX >= 0.4.30 defaults to jax_threefry_partitionable=True:
//   bits[i] = x0 ^ x1 of threefry2x32(key, (hi32(i)=0, lo32(i)=i))
// Legacy (partitionable=False) split-iota mode kept behind the macro as the
// fallback if the harness's JAX uses the old default (symptom: absmax ~ 17).
#define THREEFRY_PARTITIONABLE 1

__device__ __forceinline__ uint32_t rotl32(uint32_t v, uint32_t d) {
  return (v << d) | (v >> (32u - d));
}
__device__ __forceinline__ void tf4(uint32_t& x0, uint32_t& x1,
                                    int r0, int r1, int r2, int r3) {
  x0 += x1; x1 = rotl32(x1, r0); x1 ^= x0;
  x0 += x1; x1 = rotl32(x1, r1); x1 ^= x0;
  x0 += x1; x1 = rotl32(x1, r2); x1 ^= x0;
  x0 += x1; x1 = rotl32(x1, r3); x1 ^= x0;
}
__device__ __forceinline__ uint2 tf2x32(uint32_t x0, uint32_t x1) {
  const uint32_t K0 = 0u, K1 = 42u, K2 = (0u ^ 42u ^ 0x1BD11BDAu);
  x0 += K0; x1 += K1;
  tf4(x0, x1, 13, 15, 26, 6);   x0 += K1; x1 += K2 + 1u;
  tf4(x0, x1, 17, 29, 16, 24);  x0 += K2; x1 += K0 + 2u;
  tf4(x0, x1, 13, 15, 26, 6);   x0 += K0; x1 += K1 + 3u;
  tf4(x0, x1, 17, 29, 16, 24);  x0 += K1; x1 += K2 + 4u;
  tf4(x0, x1, 13, 15, 26, 6);   x0 += K2; x1 += K0 + 5u;
  return make_uint2(x0, x1);
}
__device__ __forceinline__ bool keep_mask(uint32_t i) {
  uint32_t b;
#if THREEFRY_PARTITIONABLE
  { uint2 r = tf2x32(0u, i); b = r.x ^ r.y; }
#else
  const uint32_t HALF = 4194304u;  // 8388608/2
  if (i < HALF) { uint2 r = tf2x32(i, i + HALF); b = r.x; }
  else          { uint2 r = tf2x32(i - HALF, i); b = r.y; }
#endif
  // jax.random.uniform bit trick, then compare against p=0.1f
  float u = __uint_as_float((b >> 9) | 0x3f800000u) - 1.0f;
  return u < 0.1f;
}

__global__ __launch_bounds__(NTHR, 2)
void attn_fused(const float* __restrict__ Q, const float* __restrict__ K,
                const float* __restrict__ V, const float* __restrict__ M,
                float* __restrict__ O)
{
  __shared__ __align__(16) float Qt[DC1][TQ];        // 2 KB  [d][q]
  __shared__ __align__(16) float Ks[DC1][SEQ];       // 16 KB [d][k]
  __shared__ __align__(16) float Wt[SEQ][WTP];       // 36 KB [k][q], padded

  const int t   = threadIdx.x;
  const int blk = blockIdx.x;
  // XCD swizzle (heuristic xcd = blk%8): the 8 q-blocks of one head share an
  // XCD so K_h+V_h (4 MB) stays L2-resident. Pure perf heuristic.
  const int a = blk & 7, b = (blk >> 3) & 7, c = blk >> 6;
  const int h  = (a << 4) | c;    // 0..127, bijective over (a,c)
  const int q0 = b * TQ;

  const float* __restrict__ Qh = Q + (size_t)h * SEQ * DIM;
  const float* __restrict__ Kh = K + (size_t)h * SEQ * DIM;
  const float* __restrict__ Vh = V + (size_t)h * SEQ * DIM;
  float* __restrict__       Oh = O + (size_t)h * SEQ * DIM;

  const int qsub = (t & 7) * 4;        // 4 q rows per thread
  const int ksub = (t >> 3) * 8;       // 8 keys per thread

  // ================= phase 1: S = Q K^T (register 4x8 tile) =================
  float acc[4][8];
  #pragma unroll
  for (int i = 0; i < 4; ++i)
    #pragma unroll
    for (int j = 0; j < 8; ++j) acc[i][j] = 0.0f;

  const int klq = t >> 2;          // 0..63  K row sub-index
  const int kld = (t & 3) * 4;     // 0..12  d offset (float4)
  const int qlq = t >> 2;          // (t<128) 0..31
  const int qld = (t & 3) * 4;

  float4 kpre[4];
  float4 qpre = make_float4(0.f, 0.f, 0.f, 0.f);
  #pragma unroll
  for (int j = 0; j < 4; ++j)
    kpre[j] = *(const float4*)(Kh + (size_t)(j * 64 + klq) * DIM + kld);
  if (t < 128)
    qpre = *(const float4*)(Qh + (size_t)(q0 + qlq) * DIM + qld);

  for (int c0 = 0; c0 < DIM / DC1; ++c0) {
    __syncthreads();
    #pragma unroll
    for (int j = 0; j < 4; ++j) {
      Ks[kld + 0][j * 64 + klq] = kpre[j].x;
      Ks[kld + 1][j * 64 + klq] = kpre[j].y;
      Ks[kld + 2][j * 64 + klq] = kpre[j].z;
      Ks[kld + 3][j * 64 + klq] = kpre[j].w;
    }
    if (t < 128) {
      Qt[qld + 0][qlq] = qpre.x;
      Qt[qld + 1][qlq] = qpre.y;
      Qt[qld + 2][qlq] = qpre.z;
      Qt[qld + 3][qlq] = qpre.w;
    }
    __syncthreads();
    const int dn = (c0 + 1) * DC1;
    if (dn < DIM) {  // prefetch next chunk; waitcnt lands at next LDS commit
      #pragma unroll
      for (int j = 0; j < 4; ++j)
        kpre[j] = *(const float4*)(Kh + (size_t)(j * 64 + klq) * DIM + dn + kld);
      if (t < 128)
        qpre = *(const float4*)(Qh + (size_t)(q0 + qlq) * DIM + dn + qld);
    }
    #pragma unroll
    for (int ds = 0; ds < DC1; ++ds) {
      float4 q4 = *(const float4*)&Qt[ds][qsub];
      float4 ka = *(const float4*)&Ks[ds][ksub];
      float4 kb = *(const float4*)&Ks[ds][ksub + 4];
      float qa[4] = {q4.x, q4.y, q4.z, q4.w};
      float kk[8] = {ka.x, ka.y, ka.z, ka.w, kb.x, kb.y, kb.z, kb.w};
      #pragma unroll
      for (int qi = 0; qi < 4; ++qi)
        #pragma unroll
        for (int kj = 0; kj < 8; ++kj)
          acc[qi][kj] = fmaf(qa[qi], kk[kj], acc[qi][kj]);
    }
  }

  // scale + mask, store transposed W[k][q]
  const float scale = 0.022097086912079608f;  // 1/sqrt(2048)
  float sv[4][8];
  #pragma unroll
  for (int qi = 0; qi < 4; ++qi) {
    const float* mrow = M + (size_t)(q0 + qsub + qi) * SEQ + ksub;
    float4 ma = *(const float4*)(mrow);
    float4 mb = *(const float4*)(mrow + 4);
    float mm[8] = {ma.x, ma.y, ma.z, ma.w, mb.x, mb.y, mb.z, mb.w};
    #pragma unroll
    for (int kj = 0; kj < 8; ++kj)
      sv[qi][kj] = fmaf(acc[qi][kj], scale, mm[kj]);
  }
  #pragma unroll
  for (int kj = 0; kj < 8; ++kj) {
    float4 w = make_float4(sv[0][kj], sv[1][kj], sv[2][kj], sv[3][kj]);
    *(float4*)&Wt[ksub + kj][qsub] = w;
  }
  __syncthreads();

  // ============== phase 2: softmax + deterministic dropout ==================
  {
    const int sq   = t >> 3;   // 0..31 local q row
    const int part = t & 7;    // 8 lanes per row, consecutive lanes
    float vals[32];
    float mx = -3.0e38f;
    #pragma unroll
    for (int j = 0; j < 32; ++j) {
      vals[j] = Wt[part * 32 + j][sq];
      mx = fmaxf(mx, vals[j]);
    }
    mx = fmaxf(mx, __shfl_xor(mx, 1));
    mx = fmaxf(mx, __shfl_xor(mx, 2));
    mx = fmaxf(mx, __shfl_xor(mx, 4));
    float l = 0.0f;
    #pragma unroll
    for (int j = 0; j < 32; ++j) {
      vals[j] = expf(vals[j] - mx);
      l += vals[j];
    }
    l += __shfl_xor(l, 1);
    l += __shfl_xor(l, 2);
    l += __shfl_xor(l, 4);
    const float wsc = 10.0f / l;   // softmax/l then /0.1 (within 1 ulp of ref)
    // flat index into (1,128,256,256): h*65536 + q*256 + k
    const uint32_t ibase = ((uint32_t)h << 16) | ((uint32_t)(q0 + sq) << 8)
                         | (uint32_t)(part * 32);
    #pragma unroll
    for (int j = 0; j < 32; ++j) {
      float wv = keep_mask(ibase + j) ? vals[j] * wsc : 0.0f;
      Wt[part * 32 + j][sq] = wv;
    }
  }
  __syncthreads();

  // ================= phase 3: out = W @ V (register 4x8 tile) ===============
  const int dsub = (t >> 3) * 8;       // 8 d columns per thread
  for (int d0 = 0; d0 < DIM; d0 += 256) {
    float acc2[4][8];
    #pragma unroll
    for (int qi = 0; qi < 4; ++qi)
      #pragma unroll
      for (int dj = 0; dj < 8; ++dj) acc2[qi][dj] = 0.0f;
    const float* vb0 = Vh + d0 + dsub;
    #pragma unroll 4
    for (int k = 0; k < SEQ; ++k) {
      float4 w4  = *(const float4*)&Wt[k][qsub];           // broadcast-ish
      float4 va  = *(const float4*)(vb0 + (size_t)k * DIM); // coalesced
      float4 vb2 = *(const float4*)(vb0 + (size_t)k * DIM + 4);
      float wq[4] = {w4.x, w4.y, w4.z, w4.w};
      float vv[8] = {va.x, va.y, va.z, va.w, vb2.x, vb2.y, vb2.z, vb2.w};
      #pragma unroll
      for (int qi = 0; qi < 4; ++qi)
        #pragma unroll
        for (int dj = 0; dj < 8; ++dj)
          acc2[qi][dj] = fmaf(wq[qi], vv[dj], acc2[qi][dj]);
    }
    #pragma unroll
    for (int qi = 0; qi < 4; ++qi) {
      float* orow = Oh + (size_t)(q0 + qsub + qi) * DIM + d0 + dsub;
      *(float4*)(orow)     = make_float4(acc2[qi][0], acc2[qi][1],
                                         acc2[qi][2], acc2[qi][3]);
      *(float4*)(orow + 4) = make_float4(acc2[qi][4], acc2[qi][5],
                                         acc2[qi][6], acc2[qi][7]);
    }
  }
}

extern "C" void kernel_launch(void* const* d_in, const int* in_sizes, int n_in,
                              void* d_out, int out_size, void* d_ws, size_t ws_size,
                              hipStream_t stream) {
  const float* Q = (const float*)d_in[0];
  const float* K = (const float*)d_in[1];
  const float* V = (const float*)d_in[2];
  const float* M = (const float*)d_in[3];
  float* O = (float*)d_out;
  hipLaunchKernelGGL(attn_fused, dim3(NH * (SEQ / TQ)), dim3(NTHR), 0, stream,
                     Q, K, V, M, O);
}